// Round 3
// baseline (297.654 us; speedup 1.0000x reference)
//
#include <hip/hip_runtime.h>

#define N_NODES 200000
#define N_EDGES 6400000
#define IN_DIM 15
#define POS_DIM 4

#define CSHIFT 9
#define CMASK 511
#define CW 512                                      // nodes per coarse bucket
#define NCOARSE ((N_NODES + CW - 1) >> CSHIFT)      // 391
#define CHUNK 16384                                 // edges per scatter block
#define NBLK ((N_EDGES + CHUNK - 1) / CHUNK)        // 391
#define CAP 17408                                   // per-bucket region capacity (mean 16384 + 8 sigma)

typedef unsigned uv4 __attribute__((ext_vector_type(4)));

// LDS float atomic: workgroup-scope relaxed fetch-add on a pointer the
// compiler knows is addrspace(3). Expected lowering: ds_add_f32.
// Worst case: CAS loop (slow but correct) -- cannot fault.
__device__ __forceinline__ void lds_fadd(float* p, float v) {
    (void)__hip_atomic_fetch_add(p, v, __ATOMIC_RELAXED, __HIP_MEMORY_SCOPE_WORKGROUP);
}

// ---------------- Pass A: per-node j-side table (+ gcnt zero) ----------------
__global__ void node_prep(const float* __restrict__ x,
                          const float* __restrict__ Wlin,
                          const float* __restrict__ Wsrc,
                          const float* __restrict__ Wpos,
                          float4* __restrict__ tabJ,
                          unsigned* __restrict__ gcnt)
{
    int n = blockIdx.x * blockDim.x + threadIdx.x;
    if (n < NCOARSE) gcnt[n] = 0u;                  // zero bucket counters inline
    if (n >= N_NODES) return;
    const float* xp = x + (long)n * IN_DIM;
    float xv[IN_DIM];
#pragma unroll
    for (int k = 0; k < IN_DIM; ++k) xv[k] = xp[k];

    float p0 = 0.f, p1 = 0.f;
#pragma unroll
    for (int k = 0; k < POS_DIM; ++k) {
        p0 += Wpos[k] * xv[k];
        p1 += Wpos[POS_DIM + k] * xv[k];
    }
    float v0 = 0.f, v1 = 0.f, as0 = 0.f, as1 = 0.f;
#pragma unroll
    for (int k = 0; k < IN_DIM; ++k) {
        float xk = xv[k];
        v0  += Wlin[k] * xk;  v1  += Wlin[IN_DIM + k] * xk;
        as0 += Wsrc[k] * xk;  as1 += Wsrc[IN_DIM + k] * xk;
    }
    tabJ[n] = make_float4(as0 + p0, as1 + p1, v0 - p0, v1 - p1);
}

// ---------------- K1: LDS-staged scatter with atomic bucket reservation -----
// Each block reserves its per-bucket span via one global atomicAdd per
// (block,bucket). Placement order within a bucket is arbitrary -- the
// aggregation is order-independent (LDS float atomics).
__global__ void scatter_kernel(const int* __restrict__ idx,
                               unsigned* __restrict__ gcnt,
                               unsigned* __restrict__ packed)
{
    __shared__ unsigned stage[CHUNK];        // 64 KB
    __shared__ unsigned cnt[512];            // counts -> cur
    __shared__ unsigned sc[512];             // scan workspace
    __shared__ unsigned lloc[512];           // exclusive local starts
    __shared__ unsigned gdst[NCOARSE];       // this block's offset within bucket
    int b = blockIdx.x;
    int t = threadIdx.x;                     // 512 threads (8 waves)
    long s0 = (long)b * CHUNK;
    int end = (int)min((long)CHUNK, (long)N_EDGES - s0);   // %2048==0
    cnt[t] = 0u;
    __syncthreads();
    // pass 1: local histogram
    for (int e = t * 4; e < end; e += 2048) {
        int4 iv = *(const int4*)(idx + s0 + e);
        atomicAdd(&cnt[iv.x >> CSHIFT], 1u);
        atomicAdd(&cnt[iv.y >> CSHIFT], 1u);
        atomicAdd(&cnt[iv.z >> CSHIFT], 1u);
        atomicAdd(&cnt[iv.w >> CSHIFT], 1u);
    }
    __syncthreads();
    // inclusive scan over 512 (1 elem/thread)
    sc[t] = cnt[t];
    __syncthreads();
    for (int o = 1; o < 512; o <<= 1) {
        unsigned a = (t >= o) ? sc[t - o] : 0u;
        __syncthreads();
        sc[t] += a;
        __syncthreads();
    }
    {
        unsigned c  = cnt[t];
        unsigned ex = sc[t] - c;             // exclusive local start
        lloc[t] = ex;
        if (t < NCOARSE) gdst[t] = atomicAdd(&gcnt[t], c);  // reserve span
        cnt[t] = ex;                         // cnt becomes cur (own entry only)
    }
    __syncthreads();
    // pass 2: place into LDS stage, bucket-major
    for (int e = t * 4; e < end; e += 2048) {
        int4 iv = *(const int4*)(idx + s0 + e);
        int4 jv = *(const int4*)(idx + N_EDGES + s0 + e);
        unsigned r0 = atomicAdd(&cnt[iv.x >> CSHIFT], 1u);
        unsigned r1 = atomicAdd(&cnt[iv.y >> CSHIFT], 1u);
        unsigned r2 = atomicAdd(&cnt[iv.z >> CSHIFT], 1u);
        unsigned r3 = atomicAdd(&cnt[iv.w >> CSHIFT], 1u);
        stage[r0] = ((unsigned)jv.x << CSHIFT) | (unsigned)(iv.x & CMASK);
        stage[r1] = ((unsigned)jv.y << CSHIFT) | (unsigned)(iv.y & CMASK);
        stage[r2] = ((unsigned)jv.z << CSHIFT) | (unsigned)(iv.z & CMASK);
        stage[r3] = ((unsigned)jv.w << CSHIFT) | (unsigned)(iv.w & CMASK);
    }
    __syncthreads();
    // pass 3: dense copy-out, one wave per bucket run (8 waves)
    int wid = t >> 6, lane = t & 63;
    for (int bk = wid; bk < NCOARSE; bk += 8) {
        unsigned st  = lloc[bk];
        unsigned len = lloc[bk + 1] - st;            // bk+1 <= 391 < 512
        unsigned gb  = gdst[bk];
        unsigned rem = (gb < (unsigned)CAP) ? (unsigned)CAP - gb : 0u;
        if (len > rem) len = rem;                    // loud-fail clamp, never hit
        unsigned* dst = packed + (size_t)bk * CAP + gb;
        for (unsigned e = lane; e < len; e += 64u)
            dst[e] = stage[st + e];
    }
}

// ---------------- K2: streaming aggregate via LDS float atomics -------------
// No counting sort: one pass over the bucket's edges, 4 ds_add_f32 per edge
// into acc[512][4] (the 4 components of a node land in 4 consecutive banks;
// random node ids spread across all 32). Block recomputes its own 512 nodes'
// logits from x (removes tabI/pvec buffers entirely). LDS = 12 KB.

struct AggState {
    float2* als;         // [512]
    float (*acc)[4];     // [512][4]
};

__device__ __forceinline__ void edge_one(unsigned w, const float2* als,
                                         float (*acc)[4],
                                         const float4* __restrict__ tabJ)
{
    unsigned r = w & CMASK;
    float4 fj = tabJ[w >> CSHIFT];
    float2 a = als[r];
    float e0 = __expf(a.x - fj.x), e1 = __expf(a.y - fj.y);
    lds_fadd(&acc[r][0], e0);
    lds_fadd(&acc[r][1], e1);
    lds_fadd(&acc[r][2], e0 * fj.z);
    lds_fadd(&acc[r][3], e1 * fj.w);
}

__global__ __launch_bounds__(512) void
bucket_agg_kernel(const unsigned* __restrict__ packed,
                  const unsigned* __restrict__ gcnt,
                  const float* __restrict__ x,
                  const float* __restrict__ Wdst,
                  const float* __restrict__ Wpos,
                  const float4* __restrict__ tabJ,
                  const float* __restrict__ bpos,
                  float2* __restrict__ out)
{
    __shared__ float2 als[512];      // A_i = a_dst_i + p_i + b  (read-only after init)
    __shared__ float  acc[512][4];   // d0,d1,n0,n1 per node, bank-interleaved
    int k = blockIdx.x;
    int t = threadIdx.x;
    float b0 = bpos[0], b1 = bpos[1];
    int gn = (k << CSHIFT) + t;

    float p0 = 0.f, p1 = 0.f, ad0 = 0.f, ad1 = 0.f;
    if (gn < N_NODES) {
        const float* xp = x + (long)gn * IN_DIM;
        float xv[IN_DIM];
#pragma unroll
        for (int q = 0; q < IN_DIM; ++q) xv[q] = xp[q];
#pragma unroll
        for (int q = 0; q < POS_DIM; ++q) {
            p0 += Wpos[q] * xv[q];
            p1 += Wpos[POS_DIM + q] * xv[q];
        }
#pragma unroll
        for (int q = 0; q < IN_DIM; ++q) {
            ad0 += Wdst[q] * xv[q];
            ad1 += Wdst[IN_DIM + q] * xv[q];
        }
    }
    als[t] = make_float2(ad0 + p0 + b0, ad1 + p1 + b1);
    acc[t][0] = 0.f; acc[t][1] = 0.f; acc[t][2] = 0.f; acc[t][3] = 0.f;
    __syncthreads();

    unsigned n = min(gcnt[k], (unsigned)CAP);     // loud-fail clamp, never hit
    const unsigned* pk = packed + (size_t)k * CAP;

    for (unsigned e = 4u * t; e < n; e += 2048u) {
        uv4 p = __builtin_nontemporal_load((const uv4*)(pk + e));   // 16B-aligned region
        if (e + 4u <= n) {
            unsigned r0 = p.x & CMASK, r1 = p.y & CMASK, r2 = p.z & CMASK, r3 = p.w & CMASK;
            float4 f0 = tabJ[p.x >> CSHIFT];   // 4 independent L2 gathers issue together
            float4 f1 = tabJ[p.y >> CSHIFT];
            float4 f2 = tabJ[p.z >> CSHIFT];
            float4 f3 = tabJ[p.w >> CSHIFT];
            float2 a0 = als[r0], a1 = als[r1], a2 = als[r2], a3 = als[r3];
            float e00 = __expf(a0.x - f0.x), e01 = __expf(a0.y - f0.y);
            float e10 = __expf(a1.x - f1.x), e11 = __expf(a1.y - f1.y);
            float e20 = __expf(a2.x - f2.x), e21 = __expf(a2.y - f2.y);
            float e30 = __expf(a3.x - f3.x), e31 = __expf(a3.y - f3.y);
            lds_fadd(&acc[r0][0], e00);        lds_fadd(&acc[r0][1], e01);
            lds_fadd(&acc[r0][2], e00 * f0.z); lds_fadd(&acc[r0][3], e01 * f0.w);
            lds_fadd(&acc[r1][0], e10);        lds_fadd(&acc[r1][1], e11);
            lds_fadd(&acc[r1][2], e10 * f1.z); lds_fadd(&acc[r1][3], e11 * f1.w);
            lds_fadd(&acc[r2][0], e20);        lds_fadd(&acc[r2][1], e21);
            lds_fadd(&acc[r2][2], e20 * f2.z); lds_fadd(&acc[r2][3], e21 * f2.w);
            lds_fadd(&acc[r3][0], e30);        lds_fadd(&acc[r3][1], e31);
            lds_fadd(&acc[r3][2], e30 * f3.z); lds_fadd(&acc[r3][3], e31 * f3.w);
        } else {
            edge_one(p.x, als, acc, tabJ);
            if (e + 1u < n) edge_one(p.y, als, acc, tabJ);
            if (e + 2u < n) edge_one(p.z, als, acc, tabJ);
        }
    }
    __syncthreads();

    if (gn >= N_NODES) return;
    float sd0 = acc[t][0], sd1 = acc[t][1], sn0 = acc[t][2], sn1 = acc[t][3];
    float o0 = (sn0 + (p0 + b0) * sd0) / (sd0 + 1e-16f);
    float o1 = (sn1 + (p1 + b1) * sd1) / (sd1 + 1e-16f);
    out[gn] = make_float2(o0, o1);
}

extern "C" void kernel_launch(void* const* d_in, const int* in_sizes, int n_in,
                              void* d_out, int out_size, void* d_ws, size_t ws_size,
                              hipStream_t stream) {
    const float* x    = (const float*)d_in[0];
    const int*   idx  = (const int*)d_in[1];   // (2, E) flat: [0..E)=i, [E..2E)=j
    const float* Wlin = (const float*)d_in[2];
    const float* Wsrc = (const float*)d_in[3];
    const float* Wdst = (const float*)d_in[4];
    const float* Wpos = (const float*)d_in[5];
    const float* bpos = (const float*)d_in[6];
    float* out = (float*)d_out;

    char* ws = (char*)d_ws;
    size_t off = 0;
    float4* tabJ = (float4*)(ws + off); off += (size_t)N_NODES * 16;        //  3.2 MB
    unsigned* packed = (unsigned*)(ws + off); off += (size_t)NCOARSE * CAP * 4;  // 27.2 MB
    unsigned* gcnt   = (unsigned*)(ws + off); off += (size_t)NCOARSE * 4;   // total ~30.4 MB (< proven 32.6)

    node_prep<<<(N_NODES + 255) / 256, 256, 0, stream>>>(x, Wlin, Wsrc, Wpos,
                                                         tabJ, gcnt);
    scatter_kernel<<<NBLK, 512, 0, stream>>>(idx, gcnt, packed);
    bucket_agg_kernel<<<NCOARSE, 512, 0, stream>>>(packed, gcnt,
                                                   x, Wdst, Wpos, tabJ, bpos,
                                                   (float2*)out);
}